// Round 6
// baseline (628.557 us; speedup 1.0000x reference)
//
#include <hip/hip_runtime.h>

#define NN 4096
#define IN_F 256
#define OUT_F 64
#define K_CH 4
#define ALPHA 0.2f
#define JP 16          // j-partitions per channel in k2 (64*16=1024 blocks -> 4/CU)
#define JCOLS 256      // NN / JP
#define ROWS1 8        // rows per k1 chunk
#define IC1 512        // NN / ROWS1 chunks per channel

typedef __bf16 bf16;
typedef __attribute__((ext_vector_type(8))) __bf16 bf16x8;
typedef __attribute__((ext_vector_type(4))) float f32x4;

// ---------------- k0: Wh = h@W (fp32) ; Wh1 = Wh@a[:64] ; Wh2 = Wh@a[64:]
__global__ __launch_bounds__(256) void k0_wh(const float* __restrict__ h,
                                             const float* __restrict__ W,
                                             const float* __restrict__ a,
                                             float* __restrict__ Wh,
                                             float* __restrict__ Wh1,
                                             float* __restrict__ Wh2) {
    int tid = threadIdx.x;
    int wave = tid >> 6, lane = tid & 63;
    int i = blockIdx.x * 4 + wave;
    const float* hrow = h + (size_t)i * IN_F;
    float acc = 0.f;
    #pragma unroll 8
    for (int c = 0; c < IN_F; ++c)
        acc += hrow[c] * W[c * OUT_F + lane];
    Wh[(size_t)i * OUT_F + lane] = acc;
    float v1 = acc * a[lane];
    float v2 = acc * a[OUT_F + lane];
    #pragma unroll
    for (int o = 32; o > 0; o >>= 1) {
        v1 += __shfl_xor(v1, o, 64);
        v2 += __shfl_xor(v2, o, 64);
    }
    if (lane == 0) { Wh1[i] = v1; Wh2[i] = v2; }
}

// ---------------- k0T: WhT[f][j] = (bf16)Wh[j][f]   (for MFMA B-fragments)
__global__ __launch_bounds__(256) void k0_transpose(const float* __restrict__ Wh,
                                                    bf16* __restrict__ WhT) {
    __shared__ float lds[OUT_F * 65];
    int tid = threadIdx.x;
    int i0 = blockIdx.x * 64;
    int f = tid & 63;
    int r0 = tid >> 6;
    #pragma unroll
    for (int s = 0; s < 16; ++s) {
        int r = r0 * 16 + s;
        lds[f * 65 + r] = Wh[(size_t)(i0 + r) * OUT_F + f];
    }
    __syncthreads();
    int f2 = tid >> 2;
    int c0 = (tid & 3) * 16;
    #pragma unroll
    for (int s = 0; s < 16; ++s) {
        int c = c0 + s;
        WhT[(size_t)f2 * NN + i0 + c] = (bf16)lds[f2 * 65 + c];
    }
}

// ---------------- k1 (per channel): partial column sums, depth-4 row prefetch.
// grid (IC1=512 chunks, 2 jhalf) x 256 = 1024 blocks -> 4/CU.
// partial[ic][j] = sum_{i in 8-row chunk} (edge>0 ? exp(leaky(Wh1[i]+Wh2[j])*edge) : 0)
__global__ __launch_bounds__(256) void k1_colsum(const float* __restrict__ edge_ch,
                                                 const float* __restrict__ Wh1,
                                                 const float* __restrict__ Wh2,
                                                 float* __restrict__ partial) {
    int tid = threadIdx.x;
    int j0 = blockIdx.y * 2048 + tid * 8;
    int ic = blockIdx.x;
    int ibase = ic * ROWS1;
    float w2[8];
    {
        f32x4 t0 = *(const f32x4*)&Wh2[j0];
        f32x4 t1 = *(const f32x4*)&Wh2[j0 + 4];
        #pragma unroll
        for (int c = 0; c < 4; ++c) { w2[c] = t0[c]; w2[c + 4] = t1[c]; }
    }
    float s[8] = {0.f, 0.f, 0.f, 0.f, 0.f, 0.f, 0.f, 0.f};
    const float* base = edge_ch + (size_t)ibase * NN + j0;
    // prefetch rows 0..3
    f32x4 r0[4], r1[4];
    #pragma unroll
    for (int t = 0; t < 4; ++t) {
        r0[t] = *(const f32x4*)(base + (size_t)t * NN);
        r1[t] = *(const f32x4*)(base + (size_t)t * NN + 4);
    }
    #pragma unroll
    for (int ii = 0; ii < ROWS1; ++ii) {
        int cur = ii & 3;
        f32x4 e0 = r0[cur], e1 = r1[cur];
        int ip = (ii + 4 < ROWS1) ? ii + 4 : ii;   // clamp: harmless reload
        r0[cur] = *(const f32x4*)(base + (size_t)ip * NN);
        r1[cur] = *(const f32x4*)(base + (size_t)ip * NN + 4);
        float wh1 = Wh1[ibase + ii];
        #pragma unroll
        for (int c = 0; c < 8; ++c) {
            float ef = c < 4 ? e0[c] : e1[c - 4];
            float xv = wh1 + w2[c];
            float lk = xv > 0.f ? xv : ALPHA * xv;
            s[c] += ef > 0.f ? __expf(lk * ef) : 0.f;
        }
    }
    float* pr = partial + (size_t)ic * NN + j0;
    f32x4 o0, o1;
    #pragma unroll
    for (int c = 0; c < 4; ++c) { o0[c] = s[c]; o1[c] = s[c + 4]; }
    *(f32x4*)pr = o0;
    *(f32x4*)(pr + 4) = o1;
}

// ---------------- k1b (per channel): s_col[j] = sum_ic partial[ic][j]
// grid 64 blocks x 256: block covers 64 j; thread (jl=tid&63, g=tid>>6) sums 128 chunks.
__global__ __launch_bounds__(256) void k1_reduce(const float* __restrict__ partial,
                                                 float* __restrict__ s_col) {
    __shared__ float red[256];
    int tid = threadIdx.x;
    int jl = tid & 63, g = tid >> 6;
    int j = blockIdx.x * 64 + jl;
    float s = 0.f;
    #pragma unroll 8
    for (int t = 0; t < IC1 / 4; ++t)
        s += partial[(size_t)(g * (IC1 / 4) + t) * NN + j];
    red[tid] = s;
    __syncthreads();
    if (tid < 64)
        s_col[j] = red[tid] + red[tid + 64] + red[tid + 128] + red[tid + 192];
}

// ---------------- k2 (per channel): fused att + att write (nontemporal) + hp = att @ Wh (MFMA)
// grid (64 itile, 16 jp) x 256 = 1024 blocks -> 4/CU. depth-4 step prefetch.
// Wave layout = mfma_f32_16x16x32_bf16 A-fragment (row i = lane&15, k = quad*8+c).
__global__ __launch_bounds__(256) void k2_fused(const float* __restrict__ edge_ch,
                                                const float* __restrict__ Wh1,
                                                const float* __restrict__ Wh2,
                                                const float* __restrict__ s_col,
                                                const bf16* __restrict__ WhT,
                                                float* __restrict__ att_ch,
                                                float* __restrict__ hp) {
    __shared__ float lds_inv[JCOLS];
    __shared__ float lds_w2[JCOLS];
    int tid = threadIdx.x;
    int itile = blockIdx.x;
    int jp = blockIdx.y;
    int jbase0 = jp * JCOLS;
    {   // per-block: 1/s and Wh2 for this j-slab into LDS (1 j per thread)
        float s0 = s_col[jbase0 + tid];
        lds_inv[tid] = s0 > 0.f ? 1.f / s0 : 0.f;
        lds_w2[tid]  = Wh2[jbase0 + tid];
    }
    __syncthreads();
    int wave = tid >> 6, lane = tid & 63;
    int n16 = lane & 15, quad = lane >> 4;
    int i_row = itile * 64 + wave * 16 + n16;
    float wh1 = Wh1[i_row];
    const size_t ebase = (size_t)i_row * NN + jbase0 + quad * 8;
    const float* eptr = edge_ch + ebase;
    float* aptr = att_ch + ebase;
    const bf16* wbase = WhT + (size_t)n16 * NN + jbase0 + quad * 8;
    f32x4 acc[4] = {};
    // prefetch steps 0..3 (step s covers local j = s*32 + quad*8 .. +7)
    f32x4 p0[4], p1[4];
    #pragma unroll
    for (int t = 0; t < 4; ++t) {
        p0[t] = *(const f32x4*)(eptr + t * 32);
        p1[t] = *(const f32x4*)(eptr + t * 32 + 4);
    }
    #pragma unroll
    for (int s = 0; s < JCOLS / 32; ++s) {
        int cur = s & 3;
        f32x4 e0 = p0[cur], e1 = p1[cur];
        int sp = (s + 4 < JCOLS / 32) ? s + 4 : s;   // clamp: harmless reload
        p0[cur] = *(const f32x4*)(eptr + sp * 32);
        p1[cur] = *(const f32x4*)(eptr + sp * 32 + 4);
        int jl = s * 32 + quad * 8;
        f32x4 iv0 = *(const f32x4*)&lds_inv[jl];
        f32x4 iv1 = *(const f32x4*)&lds_inv[jl + 4];
        f32x4 wv0 = *(const f32x4*)&lds_w2[jl];
        f32x4 wv1 = *(const f32x4*)&lds_w2[jl + 4];
        bf16x8 afrag;
        f32x4 av0, av1;
        #pragma unroll
        for (int c = 0; c < 8; ++c) {
            float ef = c < 4 ? e0[c] : e1[c - 4];
            float w2c = c < 4 ? wv0[c] : wv1[c - 4];
            float isc = c < 4 ? iv0[c] : iv1[c - 4];
            float xv = wh1 + w2c;
            float lk = xv > 0.f ? xv : ALPHA * xv;
            float attv = ef > 0.f ? __expf(lk * ef) * isc : 0.f;
            afrag[c] = (bf16)attv;
            if (c < 4) av0[c] = attv; else av1[c - 4] = attv;
        }
        __builtin_nontemporal_store(av0, (f32x4*)(aptr + s * 32));
        __builtin_nontemporal_store(av1, (f32x4*)(aptr + s * 32 + 4));
        #pragma unroll
        for (int ft = 0; ft < 4; ++ft) {
            bf16x8 bfrag = *(const bf16x8*)(wbase + (size_t)ft * 16 * NN + s * 32);
            acc[ft] = __builtin_amdgcn_mfma_f32_16x16x32_bf16(afrag, bfrag, acc[ft], 0, 0, 0);
        }
    }
    // C/D layout: col = lane&15, row = (lane>>4)*4 + reg
    #pragma unroll
    for (int ft = 0; ft < 4; ++ft) {
        #pragma unroll
        for (int r = 0; r < 4; ++r) {
            int row_l = quad * 4 + r;
            int i_g = itile * 64 + wave * 16 + row_l;
            size_t idx = ((size_t)jp * NN + i_g) * OUT_F + ft * 16 + n16;
            hp[idx] = acc[ft][r];
        }
    }
}

// ---------------- k3 (per channel): out[i][ch*64+f] = elu(sum_jp hp)
__global__ __launch_bounds__(256) void k3_combine(const float* __restrict__ hp,
                                                  float* __restrict__ out,
                                                  int kch) {
    int g = blockIdx.x * 256 + threadIdx.x;
    int i = g >> 6;
    int f = g & 63;
    float s = 0.f;
    #pragma unroll
    for (int z = 0; z < JP; ++z)
        s += hp[((size_t)z * NN + i) * OUT_F + f];
    out[(size_t)i * (K_CH * OUT_F) + kch * OUT_F + f] = s > 0.f ? s : __expf(s) - 1.f;
}

extern "C" void kernel_launch(void* const* d_in, const int* in_sizes, int n_in,
                              void* d_out, int out_size, void* d_ws, size_t ws_size,
                              hipStream_t stream) {
    (void)out_size; (void)ws_size;
    const float *h = nullptr, *edge = nullptr, *W = nullptr, *a = nullptr;
    for (int i = 0; i < n_in; ++i) {
        int sz = in_sizes[i];
        if (sz == NN * IN_F)               h    = (const float*)d_in[i];
        else if (sz == K_CH * NN * NN)     edge = (const float*)d_in[i];
        else if (sz == IN_F * OUT_F)       W    = (const float*)d_in[i];
        else if (sz == 2 * OUT_F)          a    = (const float*)d_in[i];
    }

    char* ws = (char*)d_ws;
    float* Wh      = (float*)(ws);                                   // 1 MB
    float* Wh1     = (float*)(ws + 1048576);                         // 16 KB
    float* Wh2     = (float*)(ws + 1048576 + 16384);                 // 16 KB
    float* s_col   = (float*)(ws + 1048576 + 32768);                 // 16 KB
    bf16*  WhT     = (bf16*) (ws + 1048576 + 49152);                 // 512 KB
    float* partial = (float*)(ws + 1048576 + 49152 + 524288);        // 8 MB
    float* hp      = (float*)(ws + 1048576 + 49152 + 524288 + 8388608); // 16 MB
    // total ~25.6 MB (less than the 33.5 MB proven in earlier rounds)

    float* out_h   = (float*)d_out;
    float* att_out = out_h + (size_t)NN * (K_CH * OUT_F);

    k0_wh<<<dim3(NN / 4), 256, 0, stream>>>(h, W, a, Wh, Wh1, Wh2);
    k0_transpose<<<dim3(NN / 64), 256, 0, stream>>>(Wh, WhT);

    // Per-channel pipeline: k1(ch) leaves edge_ch in L3; k2(ch) re-reads it L3-hot.
    for (int ch = 0; ch < K_CH; ++ch) {
        const float* edge_ch = edge + (size_t)ch * NN * NN;
        float* att_ch = att_out + (size_t)ch * NN * NN;
        k1_colsum<<<dim3(IC1, 2), 256, 0, stream>>>(edge_ch, Wh1, Wh2, partial);
        k1_reduce<<<dim3(NN / 64), 256, 0, stream>>>(partial, s_col);
        k2_fused<<<dim3(64, JP), 256, 0, stream>>>(edge_ch, Wh1, Wh2, s_col, WhT, att_ch, hp);
        k3_combine<<<dim3(NN * OUT_F / 256), 256, 0, stream>>>(hp, out_h, ch);
    }
}